// Round 5
// baseline (257.588 us; speedup 1.0000x reference)
//
#include <hip/hip_runtime.h>
#include <cfloat>
#include <cstddef>

// VQ-VAE vector quantizer, MI355X / gfx950.
// z: (32, 64, 32, 32) f32 BCHW; embedding: (1024, 64) f32.
// Outputs concatenated f32: loss[1], z_q(BCHW)[2097152], perplexity[1],
// min_encodings[32768*1024], min_encoding_indices(as float)[32768].
//
// Argmin: emulate the reference's fp32 rounding (NOT exact math):
//   d_j = fl32( fl32(z2 + e2_j) - 2*dot_j )  at magnitude ~64,
// with z2/e2 double-accumulated and rounded once to fp32, dot via fp32 fma
// chains (error << ulp(64)); first-index tie-break matches np.argmin.
// Passed bit-exactly (absmax 0.0) rounds 2-3 — numerics preserved verbatim.
//
// R4/R5: VGPR_Count=40 in R3 proved the 64-float z-row was NOT register-
// resident (compiler reloading from L1 / bouncing through AGPRs inside the
// j-loop -> 2x VALU issue + latency-bound at 38% VALUBusy). Pin zr into
// VGPRs with empty asm "+v" so it can't be rematerialized. R5 fixes the
// nontemporal-store type (needs a clang ext_vector, not HIP float2).

#define NROWS      32768          // B*H*W
#define NE         1024
#define EDIM       64
#define RPB        64             // rows per block
#define NBLK       (NROWS / RPB)  // 512
#define TPB        512            // 8 waves: each scans 128 codes

#define OFF_LOSS   ((size_t)0)
#define OFF_ZQ     ((size_t)1)
#define OFF_PERP   ((size_t)2097153)
#define OFF_OH     ((size_t)2097154)
#define OFF_IDX    ((size_t)35651586)

typedef float f2_t __attribute__((ext_vector_type(2)));

// ws layout (bytes): [0,2048) float partial[512]

__global__ __launch_bounds__(TPB, 4) void vq_main(const float* __restrict__ z,
                                                  const float* __restrict__ emb,
                                                  float* __restrict__ partial,
                                                  float* __restrict__ out) {
    const int t    = threadIdx.x;
    const int lane = t & 63;
    const int q    = t >> 6;          // wave id, 0..7
    const int r0   = blockIdx.x * RPB;
    const int row  = r0 + lane;       // this lane's z-row
    const int b    = row >> 10;       // batch (1024 rows per batch image)
    const int m    = row & 1023;      // h*32+w
    const size_t zbase = (size_t)b * 65536 + (size_t)m;

    __shared__ float s_e2[NE];
    __shared__ float s_d[8][64];
    __shared__ int   s_j[8][64];
    __shared__ int   s_idx[64];
    __shared__ float s_l[8];

    // ---- per-block ||e_j||^2 into LDS (double-accumulated, fp32-rounded) --
    for (int j = t; j < NE; j += TPB) {
        const float4* e4 = (const float4*)(emb + ((size_t)j << 6));
        double s = 0.0;
#pragma unroll
        for (int k = 0; k < 16; ++k) {
            float4 v = e4[k];
            s += (double)v.x * (double)v.x;
            s += (double)v.y * (double)v.y;
            s += (double)v.z * (double)v.z;
            s += (double)v.w * (double)v.w;
        }
        s_e2[j] = (float)s;
    }

    // ---- load this lane's z row (64 ch, stride 1024 floats) into VGPRs ----
    float4 zr[16];
#pragma unroll
    for (int k = 0; k < 16; ++k) {
        float4 v;
        v.x = z[zbase + (size_t)(4 * k + 0) * 1024];
        v.y = z[zbase + (size_t)(4 * k + 1) * 1024];
        v.z = z[zbase + (size_t)(4 * k + 2) * 1024];
        v.w = z[zbase + (size_t)(4 * k + 3) * 1024];
        zr[k] = v;
    }
    // Pin all 64 values into VGPRs: opaque to remat / AGPR shuffling.
#pragma unroll
    for (int k = 0; k < 16; ++k) {
        asm volatile("" : "+v"(zr[k].x), "+v"(zr[k].y),
                          "+v"(zr[k].z), "+v"(zr[k].w));
    }

    // ---- ||z||^2 in double, rounded once to fp32 ----
    double z2d = 0.0;
#pragma unroll
    for (int k = 0; k < 16; ++k) {
        z2d += (double)zr[k].x * (double)zr[k].x;
        z2d += (double)zr[k].y * (double)zr[k].y;
        z2d += (double)zr[k].z * (double)zr[k].z;
        z2d += (double)zr[k].w * (double)zr[k].w;
    }
    const float z2f = (float)z2d;

    __syncthreads();   // s_e2 ready

    // ---- scan this wave's 128-code chunk, 2 codes per iteration ----
    const int jbase = __builtin_amdgcn_readfirstlane(q << 7);
    float bestd = FLT_MAX;
    int   bestj = NE;
    for (int jj = 0; jj < 128; jj += 2) {
        const int ja = jbase + jj;
        const int jb = ja + 1;
        const float4* ea = (const float4*)(emb + ((size_t)ja << 6));
        const float4* eb = (const float4*)(emb + ((size_t)jb << 6));
        float a0 = 0.f, a1 = 0.f, a2 = 0.f, a3 = 0.f;
        float b0 = 0.f, b1 = 0.f, b2 = 0.f, b3 = 0.f;
#pragma unroll
        for (int k = 0; k < 16; ++k) {
            float4 av = ea[k];
            float4 bv = eb[k];
            a0 = fmaf(av.x, zr[k].x, a0);
            a1 = fmaf(av.y, zr[k].y, a1);
            a2 = fmaf(av.z, zr[k].z, a2);
            a3 = fmaf(av.w, zr[k].w, a3);
            b0 = fmaf(bv.x, zr[k].x, b0);
            b1 = fmaf(bv.y, zr[k].y, b1);
            b2 = fmaf(bv.z, zr[k].z, b2);
            b3 = fmaf(bv.w, zr[k].w, b3);
        }
        float dota = (a0 + a1) + (a2 + a3);
        float dotb = (b0 + b1) + (b2 + b3);
        // reference fp32 rounding sequence (two roundings at magnitude ~64)
        float da = (z2f + s_e2[ja]) - 2.0f * dota;
        float db = (z2f + s_e2[jb]) - 2.0f * dotb;
        if (da < bestd || (da == bestd && ja < bestj)) { bestd = da; bestj = ja; }
        if (db < bestd || (db == bestd && jb < bestj)) { bestd = db; bestj = jb; }
    }

    // ---- combine 8 per-wave candidates per row; first-index tie-break ----
    s_d[q][lane] = bestd;
    s_j[q][lane] = bestj;
    __syncthreads();
    if (t < 64) {
        float bd = s_d[0][t];
        int   bj = s_j[0][t];
#pragma unroll
        for (int w = 1; w < 8; ++w) {   // ascending w = ascending code chunks
            float dw = s_d[w][t];
            int   jw = s_j[w][t];
            if (dw < bd || (dw == bd && jw < bj)) { bd = dw; bj = jw; }
        }
        s_idx[t] = bj;
        out[OFF_IDX + (size_t)(r0 + t)] = (float)bj;   // indices as float
    }
    __syncthreads();

    // ---- z_q (straight-through) + loss partial ----
    // wave q handles channels c = q, q+8, ... for its lane's row
    const int    jjx = s_idx[lane];
    const float* er  = emb + ((size_t)jjx << 6);
    float* zq = out + OFF_ZQ + (size_t)b * 65536 + (size_t)m;
    float lsum = 0.f;
#pragma unroll
    for (int c = q; c < EDIM; c += 8) {
        float zc   = z[zbase + (size_t)c * 1024];   // coalesced across lanes
        float ev   = er[c];                         // gather (L2-hot)
        float diff = ev - zc;
        zq[(size_t)c * 1024] = zc + diff;           // mimic zp + (z_q - zp)
        lsum = fmaf(diff, diff, lsum);
    }
#pragma unroll
    for (int off = 32; off >= 1; off >>= 1) lsum += __shfl_down(lsum, off);
    if (lane == 0) s_l[q] = lsum;
    __syncthreads();
    if (t == 0) {
        float l = 0.f;
#pragma unroll
        for (int w = 0; w < 8; ++w) l += s_l[w];
        partial[blockIdx.x] = l;
    }

    // ---- one-hot rows: 64 rows x 1024 cols, nontemporal f2 stores ----
    // (region is 8-byte aligned -> 2-float stores; streaming, never re-read)
    float* oh = out + OFF_OH;
    for (int mm = 0; mm < RPB; ++mm) {
        int    jr   = s_idx[mm];
        float* rowp = oh + (size_t)(r0 + mm) * 1024;
        f2_t v0 = (f2_t)(0.f);
        if ((jr >> 1) == t) v0[jr & 1] = 1.0f;
        __builtin_nontemporal_store(v0, (f2_t*)rowp + t);  // cols [2t,2t+1]
    }
}

__global__ __launch_bounds__(1024) void vq_final(const float* __restrict__ partial,
                                                 float* __restrict__ out) {
    const int t = threadIdx.x;
    __shared__ int   s_hist[NE];
    __shared__ float st[16], sl[16];
    s_hist[t] = 0;
    __syncthreads();
    // rebuild histogram from the indices vq_main wrote (coalesced reads)
    const float* idxf = out + OFF_IDX;
    for (int i = t; i < NROWS; i += 1024) {
        atomicAdd(&s_hist[(int)idxf[i]], 1);
    }
    __syncthreads();
    float p    = (float)s_hist[t] * (1.0f / 32768.0f);
    float term = p * logf(p + 1e-10f);
    float lp   = (t < NBLK) ? partial[t] : 0.f;
#pragma unroll
    for (int off = 32; off >= 1; off >>= 1) {
        term += __shfl_down(term, off);
        lp   += __shfl_down(lp, off);
    }
    int w = t >> 6, ln = t & 63;
    if (ln == 0) { st[w] = term; sl[w] = lp; }
    __syncthreads();
    if (t == 0) {
        float s = 0.f, l = 0.f;
#pragma unroll
        for (int i = 0; i < 16; ++i) { s += st[i]; l += sl[i]; }
        out[OFF_LOSS] = 1.25f * l * (1.0f / 2097152.0f);  // (1+beta)*mean
        out[OFF_PERP] = expf(-s);
    }
}

extern "C" void kernel_launch(void* const* d_in, const int* in_sizes, int n_in,
                              void* d_out, int out_size, void* d_ws, size_t ws_size,
                              hipStream_t stream) {
    const float* z   = (const float*)d_in[0];
    const float* emb = (const float*)d_in[1];
    float* out     = (float*)d_out;
    float* partial = (float*)d_ws;

    vq_main<<<NBLK, TPB, 0, stream>>>(z, emb, partial, out);
    vq_final<<<1, 1024, 0, stream>>>(partial, out);
}